// Round 7
// baseline (20292.520 us; speedup 1.0000x reference)
//
#include <hip/hip_runtime.h>
#include <math.h>

#ifndef M_PI
#define M_PI 3.14159265358979323846
#endif

#define BD 256
#define NB 16
#define DIM 1024
#define SMAX 288
#define NSTEPS 32
#define NPROPS 512
#define NTOK (16 * 256 * 1024)
#define XW 16
#define GRID 256
#define SMEM_BYTES 47616

__device__ __forceinline__ double wred_sum(double v) {
#pragma unroll
    for (int o = 32; o > 0; o >>= 1) v += __shfl_down(v, o, 64);
    return v;
}
__device__ __forceinline__ double wred_max(double v) {
#pragma unroll
    for (int o = 32; o > 0; o >>= 1) { double w = __shfl_down(v, o, 64); if (w > v) v = w; }
    return v;
}
__device__ double block_sum(double v, double* sc) {
    v = wred_sum(v);
    int tid = threadIdx.x;
    if ((tid & 63) == 0) sc[tid >> 6] = v;
    __syncthreads();
    double r = sc[0] + sc[1] + sc[2] + sc[3];
    __syncthreads();
    return r;
}
__device__ double block_max(double v, double* sc) {
    v = wred_max(v);
    int tid = threadIdx.x;
    if ((tid & 63) == 0) sc[tid >> 6] = v;
    __syncthreads();
    double r = fmax(fmax(sc[0], sc[1]), fmax(sc[2], sc[3]));
    __syncthreads();
    return r;
}

// ---- software grid barrier: R4-proven primitives (threadfence + device atomics),
// sense-reversing so one (cnt,flag) pair serves all barriers. Safe because a
// block stuck spinning prevents the next barrier from completing (flag cannot
// flip again until every block arrives there).
__device__ __forceinline__ void gbar(int* cnt, int* flag, int* sense) {
    __threadfence();          // release: every thread wb's its stores (R4 pattern)
    __syncthreads();
    if (threadIdx.x == 0) {
        int s = *sense ^ 1;
        *sense = s;
        if (atomicAdd(cnt, 1) == GRID - 1) {
            atomicExch(cnt, 0);          // reset BEFORE flag release
            atomicExch(flag, s);
        } else {
            while (atomicAdd(flag, 0) != s) __builtin_amdgcn_s_sleep(16);
        }
    }
    __syncthreads();
    __threadfence();          // acquire: invalidate stale cached lines
}

// ================= setup kernels (R5-proven where noted) =================

__global__ __launch_bounds__(256) void k_tok_convert(const int* __restrict__ tok32,
                                                     signed char* __restrict__ tokc) {
    __shared__ int flag;
    int tid = threadIdx.x;
    if (tid == 0) {
        int nz = 0;
        for (int i = 1; i < 512; i += 2) nz |= tok32[i];
        flag = nz;
    }
    __syncthreads();
    bool is64 = (flag == 0);
#pragma unroll
    for (int it = 0; it < 4; ++it) {
        size_t idx = (size_t)blockIdx.x * 1024 + it * BD + tid;
        int v = is64 ? tok32[2 * idx] : tok32[idx];
        tokc[idx] = (signed char)v;
    }
}

__global__ __launch_bounds__(256) void k_pack(const signed char* __restrict__ tokc,
                                              unsigned long long* __restrict__ X) {
    int tid = threadIdx.x, lane = tid & 63, wv = tid >> 6;
    int T = blockIdx.x * 4 + wv;
    int b = T >> 8, pos = T & 255;
    for (int w = 0; w < XW; ++w) {
        signed char byte = tokc[(size_t)T * DIM + w * 64 + lane];
        unsigned long long m = __ballot(byte != 0);
        if (lane == 0) X[((size_t)b * SMAX + pos) * XW + w] = m;
    }
}

__global__ __launch_bounds__(256) void k_posstats(const unsigned long long* __restrict__ X,
        double* __restrict__ mu_pos, double* __restrict__ rs_pos) {
    int T = blockIdx.x * BD + threadIdx.x;
    int b = T >> 8, pos = T & 255;
    const unsigned long long* xw = X + ((size_t)b * SMAX + pos) * XW;
    int nbi = 0;
    for (int w = 0; w < XW; ++w) nbi += __popcll(xw[w]);
    double nb = (double)nbi;
    double m = nb * (1.0 / 1024.0);
    double var = ((1024.0 - nb) * m * m + nb * (1.0 - m) * (1.0 - m)) * (1.0 / 1024.0);
    mu_pos[b * SMAX + pos] = m;
    rs_pos[b * SMAX + pos] = 1.0 / sqrt(var + 1e-5);
}

__global__ __launch_bounds__(256) void k_init(const signed char* __restrict__ tokc,
                                              double* __restrict__ xl) {
    int b = blockIdx.x, tid = threadIdx.x;
    for (int i = tid; i < DIM; i += BD)
        xl[b * DIM + i] = (double)tokc[((size_t)b * 256 + 255) * DIM + i];
}

__global__ __launch_bounds__(256) void k_barinit(int* __restrict__ bar) {
    if (threadIdx.x < 128) bar[threadIdx.x] = 0;
}

// G_K[j]=sum_k g1[k]*Wk[k,j]; KB[j]=sum_k b1[k]*Wk[k,j]+bqkv_k[j]; same for V (R5-proven)
__global__ __launch_bounds__(256) void k_precomp(const float* __restrict__ Wqkv,
        const float* __restrict__ bqkv, const float* __restrict__ g1, const float* __restrict__ b1,
        double* __restrict__ G_K, double* __restrict__ KB,
        double* __restrict__ Gv, double* __restrict__ VB) {
    __shared__ double rg[256], rb[256];
    int tid = threadIdx.x;
    int sec = blockIdx.x >> 4;
    int jt = blockIdx.x & 15;
    int j = jt * 64 + (tid & 63);
    int kp = tid >> 6;
    double ag = 0, ab = 0;
    int cbase = 1024 + sec * 1024 + j;
    for (int k = kp * 256; k < kp * 256 + 256; ++k) {
        double w = (double)Wqkv[(size_t)k * 3072 + cbase];
        ag += (double)g1[k] * w;
        ab += (double)b1[k] * w;
    }
    rg[tid] = ag; rb[tid] = ab;
    __syncthreads();
    if (tid < 64) {
        double sg = ((rg[tid] + rg[tid + 64]) + (rg[tid + 128] + rg[tid + 192]));
        double sb = ((rb[tid] + rb[tid + 64]) + (rb[tid + 128] + rb[tid + 192]));
        double bias = (double)bqkv[cbase];
        if (sec == 0) { G_K[j] = sg; KB[j] = sb + bias; }
        else          { Gv[j]  = sg; VB[j] = sb + bias; }
    }
}

// vg[m]=Wq[m,:]·G_K, vkb[m]=Wq[m,:]·KB, ctil[k]=Wk[k,:]·bq, gv2[j]=Gv·Wap[:,j],
// vb2[j]=VB·Wap[:,j]+bap[j], scal={bq·G_K, bq·KB}
__global__ __launch_bounds__(256) void k_vecs(const float* __restrict__ Wqkv,
        const float* __restrict__ bqkv, const float* __restrict__ Wap, const float* __restrict__ bap,
        const double* __restrict__ G_K, const double* __restrict__ KB,
        const double* __restrict__ Gv, const double* __restrict__ VB,
        double* __restrict__ vg, double* __restrict__ vkb, double* __restrict__ ctil,
        double* __restrict__ gv2, double* __restrict__ vb2, double* __restrict__ scal) {
    int bid = blockIdx.x, tid = threadIdx.x;
    if (bid < 4) {
        int m = bid * 256 + tid;
        double a = 0, c = 0;
        for (int j = 0; j < DIM; ++j) {
            double w = (double)Wqkv[(size_t)m * 3072 + j];
            a += w * G_K[j]; c += w * KB[j];
        }
        vg[m] = a; vkb[m] = c;
    } else if (bid < 8) {
        int k = (bid - 4) * 256 + tid;
        double a = 0;
        for (int j = 0; j < DIM; ++j)
            a += (double)Wqkv[(size_t)k * 3072 + 1024 + j] * (double)bqkv[j];
        ctil[k] = a;
    } else if (bid < 12) {
        int j = (bid - 8) * 256 + tid;
        double a = 0, c = 0;
        for (int d = 0; d < DIM; ++d) {
            double w = (double)Wap[(size_t)d * DIM + j];
            a += Gv[d] * w; c += VB[d] * w;
        }
        gv2[j] = a; vb2[j] = c + (double)bap[j];
    } else {
        __shared__ double sc[4];
        double a = 0, c = 0;
        for (int j = tid; j < DIM; j += BD) {
            a += (double)bqkv[j] * G_K[j];
            c += (double)bqkv[j] * KB[j];
        }
        a = block_sum(a, sc);
        c = block_sum(c, sc);
        if (tid == 0) { scal[0] = a; scal[1] = c; }
    }
}

// Atil[m][k'] = sum_j Wq[m,j]*Wk[k',j]
__global__ __launch_bounds__(256) void k_AB(const float* __restrict__ Wqkv, double* __restrict__ Atil) {
    __shared__ float Af[16 * 64];
    __shared__ float Bs[64 * 65];
    int tid = threadIdx.x, tx = tid & 63, ty = tid >> 6;
    int kp0 = blockIdx.x * 64;
    int m0  = blockIdx.y * 16;
    double acc[4] = {0, 0, 0, 0};
    for (int jc = 0; jc < DIM; jc += 64) {
        __syncthreads();
#pragma unroll
        for (int it = 0; it < 4; ++it) {
            int idx = tid + it * BD; int r = idx >> 6, jj = idx & 63;
            Af[r * 64 + jj] = Wqkv[(size_t)(m0 + r) * 3072 + jc + jj];
        }
#pragma unroll
        for (int it = 0; it < 16; ++it) {
            int idx = tid + it * BD; int c = idx >> 6, jj = idx & 63;
            Bs[c * 65 + jj] = Wqkv[(size_t)(kp0 + c) * 3072 + 1024 + jc + jj];
        }
        __syncthreads();
#pragma unroll 8
        for (int jj = 0; jj < 64; ++jj) {
            double bv = (double)Bs[tx * 65 + jj];
            acc[0] += (double)Af[(ty * 4 + 0) * 64 + jj] * bv;
            acc[1] += (double)Af[(ty * 4 + 1) * 64 + jj] * bv;
            acc[2] += (double)Af[(ty * 4 + 2) * 64 + jj] * bv;
            acc[3] += (double)Af[(ty * 4 + 3) * 64 + jj] * bv;
        }
    }
#pragma unroll
    for (int a = 0; a < 4; ++a)
        Atil[(size_t)(m0 + ty * 4 + a) * DIM + kp0 + tx] = acc[a];
}

// Btil[k][j] = sum_d Wv[k,d]*Wap[d,j]
__global__ __launch_bounds__(256) void k_BB(const float* __restrict__ Wqkv,
        const float* __restrict__ Wap, double* __restrict__ Btil) {
    __shared__ float Af[16 * 64];
    __shared__ float Wsf[64 * 64];
    int tid = threadIdx.x, tx = tid & 63, ty = tid >> 6;
    int j0 = blockIdx.x * 64;
    int k0 = blockIdx.y * 16;
    double acc[4] = {0, 0, 0, 0};
    for (int dc = 0; dc < DIM; dc += 64) {
        __syncthreads();
#pragma unroll
        for (int it = 0; it < 4; ++it) {
            int idx = tid + it * BD; int r = idx >> 6, dd = idx & 63;
            Af[r * 64 + dd] = Wqkv[(size_t)(k0 + r) * 3072 + 2048 + dc + dd];
        }
#pragma unroll
        for (int it = 0; it < 16; ++it) {
            int idx = tid + it * BD; int dd = idx >> 6, j = idx & 63;
            Wsf[dd * 64 + j] = Wap[(size_t)(dc + dd) * DIM + j0 + j];
        }
        __syncthreads();
#pragma unroll 8
        for (int dd = 0; dd < 64; ++dd) {
            double w = (double)Wsf[dd * 64 + tx];
            acc[0] += (double)Af[(ty * 4 + 0) * 64 + dd] * w;
            acc[1] += (double)Af[(ty * 4 + 1) * 64 + dd] * w;
            acc[2] += (double)Af[(ty * 4 + 2) * 64 + dd] * w;
            acc[3] += (double)Af[(ty * 4 + 3) * 64 + dd] * w;
        }
    }
#pragma unroll
    for (int a = 0; a < 4; ++a)
        Btil[(size_t)(k0 + ty * 4 + a) * DIM + j0 + tx] = acc[a];
}

// ================= persistent main kernel (plain launch + software barrier) =================

struct Prm {
    unsigned long long* X;
    double *mu_pos, *rs_pos, *xl, *c2, *alpha, *x2, *hf, *mu2, *rs2;
    double *Pu, *Px2, *P3, *P4, *Atil, *Btil;
    double *ctil, *vg, *vkb, *gv2, *vb2, *scal;
    const float *g1, *b1, *g2, *b2, *gf, *bf, *bfc, *bmp, *Wfc, *Wmp, *Wsc;
    float* out;
    int *cnt, *flag;
};

// S1: u-partials = ln1(xl) @ Atil  (16 jt x 16 ks tiles); in-block closed-form stats
__device__ void s1_u(const Prm& p, char* sm, int bid, int t) {
    double* As  = (double*)sm;            // 8192
    double* Ws  = (double*)(sm + 8192);   // 32768
    double* mu1 = (double*)(sm + 40960);  // 128
    double* rs1 = (double*)(sm + 41088);  // 128
    int*    pc  = (int*)(sm + 41216);     // 1024
    int tid = threadIdx.x;
    int posq = 255 + t;
    {
        int row = tid >> 4, w = tid & 15;
        pc[tid] = __popcll(p.X[((size_t)row * SMAX + posq) * XW + w]);
    }
    __syncthreads();
    if (tid < NB) {
        int nb = 0;
        for (int w = 0; w < 16; ++w) nb += pc[tid * 16 + w];
        double nbd = (double)nb, m = nbd * (1.0 / 1024.0);
        double var = ((1024.0 - nbd) * m * m + nbd * (1.0 - m) * (1.0 - m)) * (1.0 / 1024.0);
        double rsv = 1.0 / sqrt(var + 1e-5);
        mu1[tid] = m; rs1[tid] = rsv;
        if (bid == 0) { p.mu_pos[tid * SMAX + posq] = m; p.rs_pos[tid * SMAX + posq] = rsv; }
    }
    __syncthreads();
    int jt = bid >> 4, ks = bid & 15;
    int j0 = jt * 64, k0 = ks * 64;
    int tx = tid & 63, ty = tid >> 6;
#pragma unroll
    for (int it = 0; it < 4; ++it) {
        int idx = tid + it * BD; int r = idx >> 6, k = idx & 63;
        int kg = k0 + k;
        As[r * 64 + k] = (p.xl[r * DIM + kg] - mu1[r]) * rs1[r] * (double)p.g1[kg] + (double)p.b1[kg];
    }
#pragma unroll
    for (int it = 0; it < 16; ++it) {
        int idx = tid + it * BD; int k = idx >> 6, j = idx & 63;
        Ws[k * 64 + j] = p.Atil[(size_t)(k0 + k) * DIM + j0 + j];
    }
    __syncthreads();
    double a0 = 0, a1 = 0, a2 = 0, a3 = 0;
#pragma unroll 8
    for (int k = 0; k < 64; ++k) {
        double w = Ws[k * 64 + tx];
        a0 += As[(ty * 4 + 0) * 64 + k] * w;
        a1 += As[(ty * 4 + 1) * 64 + k] * w;
        a2 += As[(ty * 4 + 2) * 64 + k] * w;
        a3 += As[(ty * 4 + 3) * 64 + k] * w;
    }
    p.Pu[((size_t)(ks * 16 + ty * 4 + 0)) * DIM + j0 + tx] = a0;
    p.Pu[((size_t)(ks * 16 + ty * 4 + 1)) * DIM + j0 + tx] = a1;
    p.Pu[((size_t)(ks * 16 + ty * 4 + 2)) * DIM + j0 + tx] = a2;
    p.Pu[((size_t)(ks * 16 + ty * 4 + 3)) * DIM + j0 + tx] = a3;
}

// S2: per-batch attention; dense bit-test scores (R5-verified formulas)
__device__ void s2_attn(const Prm& p, char* sm, int bid, int t) {
    if (bid >= NB) return;
    int S = 256 + t, posq = 255 + t;
    int b = bid, tid = threadIdx.x;
    unsigned long long* X_s = (unsigned long long*)sm;   // 36864
    double* u_s = (double*)(sm + 36864);                 // 8192
    double* s_s = (double*)(sm + 45056);                 // 2304
    double* sc  = (double*)(sm + 47360);                 // 32
    for (int i = tid; i < S * XW; i += BD) X_s[i] = p.X[(size_t)b * SMAX * XW + i];
    for (int k = tid; k < DIM; k += BD) {
        double s = p.ctil[k];
        for (int ks = 0; ks < 16; ++ks) s += p.Pu[((size_t)(ks * 16 + b)) * DIM + k];
        u_s[k] = (double)p.g1[k] * s;
    }
    __syncthreads();
    double mu1 = p.mu_pos[b * SMAX + posq], rs1v = p.rs_pos[b * SMAX + posq];
    double qg = 0, qkb = 0;
    for (int m = tid; m < DIM; m += BD) {
        double h = (p.xl[b * DIM + m] - mu1) * rs1v * (double)p.g1[m] + (double)p.b1[m];
        qg += h * p.vg[m];
        qkb += h * p.vkb[m];
    }
    qg = block_sum(qg, sc) + p.scal[0];
    qkb = block_sum(qkb, sc) + p.scal[1];
    int lane = tid & 63, wv = tid >> 6;
    double upre[XW];
#pragma unroll
    for (int w = 0; w < XW; ++w) upre[w] = u_s[w * 64 + lane];
    for (int pos = wv; pos < S; pos += 4) {
        double sel = 0;
#pragma unroll
        for (int w = 0; w < XW; ++w) {
            unsigned long long xw = X_s[pos * XW + w];
            sel += ((xw >> lane) & 1ull) ? upre[w] : 0.0;
        }
        sel = wred_sum(sel);
        if (lane == 0) {
            double rp = p.rs_pos[b * SMAX + pos], mp = p.mu_pos[b * SMAX + pos];
            s_s[pos] = (rp * sel - rp * mp * qg + qkb) * 0.03125;
        }
    }
    __syncthreads();
    double lm = -1e300;
    if (tid < S) lm = s_s[tid];
    if (tid + BD < S) lm = fmax(lm, s_s[tid + BD]);
    double M = block_max(lm, sc);
    double den = 0, ah = 0;
#pragma unroll
    for (int r = 0; r < 2; ++r) {
        int pos = tid + r * BD;
        if (pos < S) {
            double e = exp(s_s[pos] - M);
            double rp = p.rs_pos[b * SMAX + pos], mp = p.mu_pos[b * SMAX + pos];
            den += e; ah -= e * rp * mp;
            s_s[pos] = e * rp;
        }
    }
    den = block_sum(den, sc);
    ah = block_sum(ah, sc);
#pragma unroll
    for (int r = 0; r < 4; ++r) {
        int k = tid + r * BD;
        int w = k >> 6, bit = k & 63;
        double cc = 0;
        for (int pos = 0; pos < S; ++pos) {
            unsigned long long xw = X_s[pos * XW + w];
            cc += ((xw >> bit) & 1ull) ? s_s[pos] : 0.0;
        }
        p.c2[b * DIM + k] = (double)p.g1[k] * cc / den;
    }
    if (tid == 0) p.alpha[b] = ah / den;
}

// S3: Px2-partials = c2 @ Btil (16 jt x 16 ks)
__device__ void s3_x2(const Prm& p, char* sm, int bid) {
    double* As = (double*)sm;
    double* Ws = (double*)(sm + 8192);
    int tid = threadIdx.x;
    int jt = bid >> 4, ks = bid & 15;
    int j0 = jt * 64, k0 = ks * 64;
    int tx = tid & 63, ty = tid >> 6;
#pragma unroll
    for (int it = 0; it < 4; ++it) {
        int idx = tid + it * BD; int r = idx >> 6, k = idx & 63;
        As[r * 64 + k] = p.c2[r * DIM + k0 + k];
    }
#pragma unroll
    for (int it = 0; it < 16; ++it) {
        int idx = tid + it * BD; int k = idx >> 6, j = idx & 63;
        Ws[k * 64 + j] = p.Btil[(size_t)(k0 + k) * DIM + j0 + j];
    }
    __syncthreads();
    double a0 = 0, a1 = 0, a2 = 0, a3 = 0;
#pragma unroll 8
    for (int k = 0; k < 64; ++k) {
        double w = Ws[k * 64 + tx];
        a0 += As[(ty * 4 + 0) * 64 + k] * w;
        a1 += As[(ty * 4 + 1) * 64 + k] * w;
        a2 += As[(ty * 4 + 2) * 64 + k] * w;
        a3 += As[(ty * 4 + 3) * 64 + k] * w;
    }
    p.Px2[((size_t)(ks * 16 + ty * 4 + 0)) * DIM + j0 + tx] = a0;
    p.Px2[((size_t)(ks * 16 + ty * 4 + 1)) * DIM + j0 + tx] = a1;
    p.Px2[((size_t)(ks * 16 + ty * 4 + 2)) * DIM + j0 + tx] = a2;
    p.Px2[((size_t)(ks * 16 + ty * 4 + 3)) * DIM + j0 + tx] = a3;
}

// S4: x2 = xl + sum(Px2) + alpha*gv2 + vb2; ln2 stats
__device__ void s4_fold(const Prm& p, char* sm, int bid) {
    if (bid >= NB) return;
    int b = bid, tid = threadIdx.x;
    double* xs = (double*)sm;
    double* sc = (double*)(sm + 8192);
    double al = p.alpha[b];
    for (int i = tid; i < DIM; i += BD) {
        double s = p.xl[b * DIM + i] + al * p.gv2[i] + p.vb2[i];
        for (int ks = 0; ks < 16; ++ks) s += p.Px2[((size_t)(ks * 16 + b)) * DIM + i];
        xs[i] = s; p.x2[b * DIM + i] = s;
    }
    __syncthreads();
    double s = 0;
    for (int i = tid; i < DIM; i += BD) s += xs[i];
    s = block_sum(s, sc);
    double m = s * (1.0 / 1024.0);
    double ss = 0;
    for (int i = tid; i < DIM; i += BD) { double d = xs[i] - m; ss += d * d; }
    ss = block_sum(ss, sc);
    if (tid == 0) { p.mu2[b] = m; p.rs2[b] = 1.0 / sqrt(ss * (1.0 / 1024.0) + 1e-5); }
}

// S5: fc GEMM 512 tiles (64 jt x 8 ks, klen 128), ln2-apply in A-stage
__device__ void s5_fc(const Prm& p, char* sm, int bid) {
    double* As  = (double*)sm;
    float* Wsf  = (float*)(sm + 8192);
    double* mu2 = (double*)(sm + 8192 + 16384);
    double* rs2 = (double*)(sm + 8192 + 16384 + 128);
    int tid = threadIdx.x;
    if (tid < NB) { mu2[tid] = p.mu2[tid]; rs2[tid] = p.rs2[tid]; }
    int tx = tid & 63, ty = tid >> 6;
    for (int tile = bid; tile < 512; tile += GRID) {
        int jt = tile >> 3, ks = tile & 7;
        int j0 = jt * 64, k0 = ks * 128;
        double a0 = 0, a1 = 0, a2 = 0, a3 = 0;
        for (int kc = 0; kc < 128; kc += 64) {
            __syncthreads();
#pragma unroll
            for (int it = 0; it < 4; ++it) {
                int idx = tid + it * BD; int r = idx >> 6, k = idx & 63;
                int kg = k0 + kc + k;
                As[r * 64 + k] = (p.x2[r * DIM + kg] - mu2[r]) * rs2[r] * (double)p.g2[kg] + (double)p.b2[kg];
            }
#pragma unroll
            for (int it = 0; it < 16; ++it) {
                int idx = tid + it * BD; int k = idx >> 6, j = idx & 63;
                Wsf[k * 64 + j] = p.Wfc[(size_t)(k0 + kc + k) * 4096 + j0 + j];
            }
            __syncthreads();
#pragma unroll 8
            for (int k = 0; k < 64; ++k) {
                double w = (double)Wsf[k * 64 + tx];
                a0 += As[(ty * 4 + 0) * 64 + k] * w;
                a1 += As[(ty * 4 + 1) * 64 + k] * w;
                a2 += As[(ty * 4 + 2) * 64 + k] * w;
                a3 += As[(ty * 4 + 3) * 64 + k] * w;
            }
        }
        p.P3[((size_t)(ks * 16 + ty * 4 + 0)) * 4096 + j0 + tx] = a0;
        p.P3[((size_t)(ks * 16 + ty * 4 + 1)) * 4096 + j0 + tx] = a1;
        p.P3[((size_t)(ks * 16 + ty * 4 + 2)) * 4096 + j0 + tx] = a2;
        p.P3[((size_t)(ks * 16 + ty * 4 + 3)) * 4096 + j0 + tx] = a3;
    }
}

// S6: mproj (16 jt x 16 ks, klen 256), gelu-fold in A-stage; block 0 zeroes X row
__device__ void s6_mp(const Prm& p, char* sm, int bid, int t) {
    double* As = (double*)sm;
    float* Wsf = (float*)(sm + 8192);
    int tid = threadIdx.x;
    if (bid == 0) {
        int bb = tid >> 4, w = tid & 15;
        p.X[((size_t)bb * SMAX + 256 + t) * XW + w] = 0ull;
    }
    int jt = bid >> 4, ks = bid & 15;
    int j0 = jt * 64, k0 = ks * 256;
    int tx = tid & 63, ty = tid >> 6;
    double cgel = sqrt(2.0 / M_PI);
    double a0 = 0, a1 = 0, a2 = 0, a3 = 0;
    for (int kc = 0; kc < 256; kc += 64) {
        __syncthreads();
#pragma unroll
        for (int it = 0; it < 4; ++it) {
            int idx = tid + it * BD; int r = idx >> 6, k = idx & 63;
            int kg = k0 + kc + k;
            double u = (double)p.bfc[kg];
            for (int ps = 0; ps < 8; ++ps) u += p.P3[((size_t)(ps * 16 + r)) * 4096 + kg];
            double inner = cgel * (u + 0.044715 * u * u * u);
            As[r * 64 + k] = 0.5 * u * (1.0 + tanh(inner));
        }
#pragma unroll
        for (int it = 0; it < 16; ++it) {
            int idx = tid + it * BD; int k = idx >> 6, j = idx & 63;
            Wsf[k * 64 + j] = p.Wmp[(size_t)(k0 + kc + k) * DIM + j0 + j];
        }
        __syncthreads();
#pragma unroll 8
        for (int k = 0; k < 64; ++k) {
            double w = (double)Wsf[k * 64 + tx];
            a0 += As[(ty * 4 + 0) * 64 + k] * w;
            a1 += As[(ty * 4 + 1) * 64 + k] * w;
            a2 += As[(ty * 4 + 2) * 64 + k] * w;
            a3 += As[(ty * 4 + 3) * 64 + k] * w;
        }
    }
    p.P4[((size_t)(ks * 16 + ty * 4 + 0)) * DIM + j0 + tx] = a0;
    p.P4[((size_t)(ks * 16 + ty * 4 + 1)) * DIM + j0 + tx] = a1;
    p.P4[((size_t)(ks * 16 + ty * 4 + 2)) * DIM + j0 + tx] = a2;
    p.P4[((size_t)(ks * 16 + ty * 4 + 3)) * DIM + j0 + tx] = a3;
}

// S7: x3 = x2 + sum(P4) + bmp; lnf -> hf
__device__ void s7_lnf(const Prm& p, char* sm, int bid) {
    if (bid >= NB) return;
    int b = bid, tid = threadIdx.x;
    double* xs = (double*)sm;
    double* sc = (double*)(sm + 8192);
    for (int i = tid; i < DIM; i += BD) {
        double s = p.x2[b * DIM + i] + (double)p.bmp[i];
        for (int ks = 0; ks < 16; ++ks) s += p.P4[((size_t)(ks * 16 + b)) * DIM + i];
        xs[i] = s;
    }
    __syncthreads();
    double s = 0;
    for (int i = tid; i < DIM; i += BD) s += xs[i];
    s = block_sum(s, sc);
    double m = s * (1.0 / 1024.0);
    double ss = 0;
    for (int i = tid; i < DIM; i += BD) { double d = xs[i] - m; ss += d * d; }
    ss = block_sum(ss, sc);
    double r = 1.0 / sqrt(ss * (1.0 / 1024.0) + 1e-5);
    for (int i = tid; i < DIM; i += BD)
        p.hf[b * DIM + i] = (xs[i] - m) * r * (double)p.gf[i] + (double)p.bf[i];
}

// S8: score GEMM full-K (16 blocks, 32-col tiles) + out + threshold + bits
__device__ void s8_sc(const Prm& p, char* sm, int bid, int t) {
    if (bid >= 16) return;
    double* As = (double*)sm;
    float* Wsf = (float*)(sm + 8192);
    int tid = threadIdx.x;
    int j0 = bid * 32;
    int tx = tid & 31, ty = tid >> 5;
    double acc0 = 0, acc1 = 0;
    for (int kc = 0; kc < DIM; kc += 64) {
        __syncthreads();
#pragma unroll
        for (int it = 0; it < 4; ++it) {
            int idx = tid + it * BD; int r = idx >> 6, k = idx & 63;
            As[r * 64 + k] = p.hf[r * DIM + kc + k];
        }
#pragma unroll
        for (int it = 0; it < 8; ++it) {
            int idx = tid + it * BD; int j = idx >> 6, k = idx & 63;
            Wsf[k * 33 + j] = p.Wsc[(size_t)(j0 + j) * DIM + kc + k];
        }
        __syncthreads();
#pragma unroll 8
        for (int k = 0; k < 64; ++k) {
            double w = (double)Wsf[k * 33 + tx];
            acc0 += As[(ty * 2 + 0) * 64 + k] * w;
            acc1 += As[(ty * 2 + 1) * 64 + k] * w;
        }
    }
    int col = j0 + tx;
#pragma unroll
    for (int rr = 0; rr < 2; ++rr) {
        int r = ty * 2 + rr;
        double acc = rr ? acc1 : acc0;
        p.out[((size_t)r * NSTEPS + t) * NPROPS + col] = (float)acc;
        p.xl[r * DIM + col] = 0.0;
        bool bit = (acc > 0.0);
        p.xl[r * DIM + 512 + col] = bit ? 1.0 : 0.0;
        if (bit) atomicOr(&p.X[((size_t)r * SMAX + 256 + t) * XW + 8 + (col >> 6)],
                          1ull << (col & 63));
    }
}

__global__ __launch_bounds__(256, 1) void k_main(Prm p) {
    __shared__ __align__(16) char sm[SMEM_BYTES];
    __shared__ int sense;
    if (threadIdx.x == 0) sense = 0;
    __syncthreads();
    int bid = blockIdx.x;
    for (int t = 0; t < NSTEPS; ++t) {
        s1_u(p, sm, bid, t);     gbar(p.cnt, p.flag, &sense);
        s2_attn(p, sm, bid, t);  gbar(p.cnt, p.flag, &sense);
        s3_x2(p, sm, bid);       gbar(p.cnt, p.flag, &sense);
        s4_fold(p, sm, bid);     gbar(p.cnt, p.flag, &sense);
        s5_fc(p, sm, bid);       gbar(p.cnt, p.flag, &sense);
        s6_mp(p, sm, bid, t);    gbar(p.cnt, p.flag, &sense);
        s7_lnf(p, sm, bid);      gbar(p.cnt, p.flag, &sense);
        s8_sc(p, sm, bid, t);    gbar(p.cnt, p.flag, &sense);
    }
}

extern "C" void kernel_launch(void* const* d_in, const int* in_sizes, int n_in,
                              void* d_out, int out_size, void* d_ws, size_t ws_size,
                              hipStream_t stream) {
    const int*   tok  = (const int*)d_in[0];
    const float* Wqkv = (const float*)d_in[1];
    const float* bqkv = (const float*)d_in[2];
    const float* Wap  = (const float*)d_in[3];
    const float* bap  = (const float*)d_in[4];
    const float* g1   = (const float*)d_in[5];
    const float* b1   = (const float*)d_in[6];
    const float* g2   = (const float*)d_in[7];
    const float* b2   = (const float*)d_in[8];
    const float* Wfc  = (const float*)d_in[9];
    const float* bfc  = (const float*)d_in[10];
    const float* Wmp  = (const float*)d_in[11];
    const float* bmp  = (const float*)d_in[12];
    const float* gf   = (const float*)d_in[13];
    const float* bf   = (const float*)d_in[14];
    const float* Wsc  = (const float*)d_in[15];

    char* w = (char*)d_ws;
    size_t off = 0;
    auto alloc = [&](size_t bytes) -> void* {
        void* p = (void*)(w + off);
        off += (bytes + 255) & ~(size_t)255;
        return p;
    };
    Prm prm;
    prm.X      = (unsigned long long*)alloc((size_t)NB * SMAX * XW * 8);
    prm.mu_pos = (double*)alloc((size_t)NB * SMAX * 8);
    prm.rs_pos = (double*)alloc((size_t)NB * SMAX * 8);
    prm.xl     = (double*)alloc((size_t)NB * DIM * 8);
    prm.c2     = (double*)alloc((size_t)NB * DIM * 8);
    prm.alpha  = (double*)alloc(NB * 8);
    prm.x2     = (double*)alloc((size_t)NB * DIM * 8);
    prm.hf     = (double*)alloc((size_t)NB * DIM * 8);
    prm.mu2    = (double*)alloc(NB * 8);
    prm.rs2    = (double*)alloc(NB * 8);
    prm.Pu     = (double*)alloc((size_t)16 * NB * DIM * 8);
    prm.Px2    = (double*)alloc((size_t)16 * NB * DIM * 8);
    prm.P3     = (double*)alloc((size_t)8 * NB * 4096 * 8);
    prm.P4     = (double*)alloc((size_t)16 * NB * DIM * 8);
    prm.Atil   = (double*)alloc((size_t)DIM * DIM * 8);
    prm.Btil   = (double*)alloc((size_t)DIM * DIM * 8);
    prm.ctil   = (double*)alloc(DIM * 8);
    prm.vg     = (double*)alloc(DIM * 8);
    prm.vkb    = (double*)alloc(DIM * 8);
    prm.gv2    = (double*)alloc(DIM * 8);
    prm.vb2    = (double*)alloc(DIM * 8);
    prm.scal   = (double*)alloc(64);
    int* bar   = (int*)alloc(512);     // cnt at +0, flag at +256 (separate lines)
    double* G_K = (double*)alloc(DIM * 8);
    double* KB  = (double*)alloc(DIM * 8);
    double* Gv  = (double*)alloc(DIM * 8);
    double* VB  = (double*)alloc(DIM * 8);
    signed char* tokc = (signed char*)alloc((size_t)NTOK);
    if (off > ws_size) return;  // fail visibly

    prm.cnt = bar; prm.flag = bar + 64;
    prm.g1 = g1; prm.b1 = b1; prm.g2 = g2; prm.b2 = b2;
    prm.gf = gf; prm.bf = bf; prm.bfc = bfc; prm.bmp = bmp;
    prm.Wfc = Wfc; prm.Wmp = Wmp; prm.Wsc = Wsc;
    prm.out = (float*)d_out;

    k_barinit<<<1, BD, 0, stream>>>(bar);
    k_tok_convert<<<4096, BD, 0, stream>>>(tok, tokc);
    k_pack<<<1024, BD, 0, stream>>>(tokc, prm.X);
    k_posstats<<<16, BD, 0, stream>>>(prm.X, prm.mu_pos, prm.rs_pos);
    k_init<<<NB, BD, 0, stream>>>(tokc, prm.xl);
    k_precomp<<<32, BD, 0, stream>>>(Wqkv, bqkv, g1, b1, G_K, KB, Gv, VB);
    k_vecs<<<13, BD, 0, stream>>>(Wqkv, bqkv, Wap, bap, G_K, KB, Gv, VB,
                                  prm.vg, prm.vkb, prm.ctil, prm.gv2, prm.vb2, prm.scal);
    k_AB<<<dim3(16, 64), BD, 0, stream>>>(Wqkv, prm.Atil);
    k_BB<<<dim3(16, 64), BD, 0, stream>>>(Wqkv, Wap, prm.Btil);

    k_main<<<GRID, BD, 0, stream>>>(prm);
}